// Round 11
// baseline (251.165 us; speedup 1.0000x reference)
//
#include <hip/hip_runtime.h>
#include <hip/hip_bf16.h>

#define C 128

typedef short s16x8 __attribute__((ext_vector_type(8)));
typedef float f32x4 __attribute__((ext_vector_type(4)));

static __device__ __forceinline__ float b2f(unsigned short u) {
    union { unsigned int i; float f; } v;
    v.i = ((unsigned int)u) << 16;
    return v.f;
}
static __device__ __forceinline__ unsigned short f2b(float f) {
    __hip_bfloat16 b = __float2bfloat16(f);   // RNE
    return *reinterpret_cast<unsigned short*>(&b);
}

// ---------------- zero ints (int4) ----------------
__global__ __launch_bounds__(256) void zero_int_kernel(int4* __restrict__ p, long n4) {
    long i = blockIdx.x * 256L + threadIdx.x;
    if (i < n4) p[i] = make_int4(0, 0, 0, 0);
}

// ---------------- degree histograms, 4 edges/thread ----------------
__global__ __launch_bounds__(256) void hist_kernel(
    const int* __restrict__ ei, int E,
    int* __restrict__ degs, int* __restrict__ degd) {
    int i = blockIdx.x * 256 + threadIdx.x;
    int e0 = i * 4;
    if (e0 + 4 <= E) {
        int4 s = *(const int4*)(ei + e0);
        int4 d = *(const int4*)(ei + E + e0);
        atomicAdd(&degs[s.x], 1); atomicAdd(&degs[s.y], 1);
        atomicAdd(&degs[s.z], 1); atomicAdd(&degs[s.w], 1);
        atomicAdd(&degd[d.x], 1); atomicAdd(&degd[d.y], 1);
        atomicAdd(&degd[d.z], 1); atomicAdd(&degd[d.w], 1);
    } else {
        for (int e = e0; e < E; ++e) {
            atomicAdd(&degs[ei[e]], 1);
            atomicAdd(&degd[ei[E + e]], 1);
        }
    }
}

// ---------------- W transpose -> bf16 + coef (one-time, tiny) ----------------
__global__ __launch_bounds__(256) void wt_kernel(const float* __restrict__ W,
                                                 unsigned short* __restrict__ WtB,
                                                 const float* __restrict__ log_scale,
                                                 const float* __restrict__ hop_logits,
                                                 float* __restrict__ coef) {
    int tid = blockIdx.x * 256 + threadIdx.x;   // 16384 threads
    int k = tid & 127, c = tid >> 7;
    WtB[c * 128 + k] = f2b(W[k * 128 + c]);
    if (tid == 0) {
        float s = expf(log_scale[0]);
        float m = hop_logits[0];
        for (int kk = 1; kk < 4; ++kk) m = fmaxf(m, hop_logits[kk]);
        float a[4], sum = 0.0f;
        for (int kk = 0; kk < 4; ++kk) { a[kk] = expf(hop_logits[kk] - m); sum += a[kk]; }
        for (int kk = 0; kk < 4; ++kk) coef[kk] = (a[kk] / sum) * expf(-s * (float)kk);
    }
}

// ---------------- fused rp: block scan + atomic global base ----------------
// CSR regions need only be contiguous per node, not ordered: base via atomicAdd.
__global__ __launch_bounds__(256) void rpscan_kernel(const int* __restrict__ degd,
                                                     int* __restrict__ rp,
                                                     int* __restrict__ cursor,
                                                     int* __restrict__ gctr, int N) {
    __shared__ int sm[256];
    __shared__ int base_sm;
    int t = threadIdx.x;
    int i = blockIdx.x * 256 + t;
    int v = (i < N) ? degd[i] : 0;
    sm[t] = v;
    __syncthreads();
    for (int off = 1; off < 256; off <<= 1) {
        int add = (t >= off) ? sm[t - off] : 0;
        __syncthreads();
        sm[t] += add;
        __syncthreads();
    }
    if (t == 255) base_sm = atomicAdd(gctr, sm[255]);
    __syncthreads();
    if (i < N) {
        int r = base_sm + sm[t] - v;
        rp[i] = r;
        cursor[i] = r;
    }
}

// ---------------- scatter edges into CSR (by dst), 4 edges/thread, inline weight ----------------
__global__ __launch_bounds__(256) void scatter_kernel(const int* __restrict__ ei, int E,
                                                      int* __restrict__ cursor,
                                                      const int* __restrict__ degs,
                                                      int2* __restrict__ csr) {
    int i = blockIdx.x * 256 + threadIdx.x;
    int e0 = i * 4;
    if (e0 + 4 <= E) {
        int4 s = *(const int4*)(ei + e0);
        int4 d = *(const int4*)(ei + E + e0);
        float w0 = rsqrtf((float)degs[s.x]);   // deg_src >= 1 by construction
        float w1 = rsqrtf((float)degs[s.y]);
        float w2 = rsqrtf((float)degs[s.z]);
        float w3 = rsqrtf((float)degs[s.w]);
        int p0 = atomicAdd(&cursor[d.x], 1);
        int p1 = atomicAdd(&cursor[d.y], 1);
        int p2 = atomicAdd(&cursor[d.z], 1);
        int p3 = atomicAdd(&cursor[d.w], 1);
        csr[p0] = make_int2(s.x, __float_as_int(w0));
        csr[p1] = make_int2(s.y, __float_as_int(w1));
        csr[p2] = make_int2(s.z, __float_as_int(w2));
        csr[p3] = make_int2(s.w, __float_as_int(w3));
    } else {
        for (int e = e0; e < E; ++e) {
            int s = ei[e];
            int d = ei[E + e];
            float w = rsqrtf((float)degs[s]);
            int pos = atomicAdd(&cursor[d], 1);
            csr[pos] = make_int2(s, __float_as_int(w));
        }
    }
}

// ---------------- pull1: f32 src, 2 rows per gather instruction ----------------
// lane: g = lane>>5 (edge slot), ls = lane&31 (element quad). 8 edges/iter, MLP 4.
__global__ __launch_bounds__(256) void pull1_kernel(
    const int* __restrict__ rp, const int* __restrict__ degd,
    const int2* __restrict__ csr,
    const float* __restrict__ x, unsigned int* __restrict__ nxt, int N) {
    int wid = (int)((blockIdx.x * 256L + threadIdx.x) >> 6);
    if (wid >= N) return;
    int lane = threadIdx.x & 63;
    int g  = lane >> 5;       // 0..1
    int ls = lane & 31;       // elems [4ls, 4ls+4)
    int beg = __builtin_amdgcn_readfirstlane(rp[wid]);
    int cnt = __builtin_amdgcn_readfirstlane(degd[wid]);
    float a0 = 0.f, a1 = 0.f, a2 = 0.f, a3 = 0.f;
    if (cnt > 0) {
        for (int j = 0; j < cnt; j += 8) {
            #pragma unroll
            for (int h = 0; h < 4; ++h) {
                int jj = j + 2 * h + g;
                bool ok = jj < cnt;
                int2 e = csr[beg + (ok ? jj : 0)];
                float w = ok ? __int_as_float(e.y) : 0.0f;
                float4 v = *(const float4*)(x + (long)e.x * C + ls * 4);
                a0 += w * v.x; a1 += w * v.y; a2 += w * v.z; a3 += w * v.w;
            }
        }
        a0 += __shfl_xor(a0, 32, 64);
        a1 += __shfl_xor(a1, 32, 64);
        a2 += __shfl_xor(a2, 32, 64);
        a3 += __shfl_xor(a3, 32, 64);
        float dv = rsqrtf((float)cnt);
        a0 *= dv; a1 *= dv; a2 *= dv; a3 *= dv;
    }
    if (g == 0) {
        uint2 o;
        o.x = (unsigned int)f2b(a0) | ((unsigned int)f2b(a1) << 16);
        o.y = (unsigned int)f2b(a2) | ((unsigned int)f2b(a3) << 16);
        *(uint2*)((unsigned short*)nxt + (long)wid * C + ls * 4) = o;
    }
}

// ---------------- pull2 / pull3c: bf16 src, 4 rows per gather instruction ----------------
// lane: g = lane>>4 (edge slot), ls = lane&15 (element octet). 8 edges/iter, MLP 2.
// COMBINE: also fuse hc = bf16(c0*x + c1*h1 + c2*h2 + c3*acc) (pull3).
template<int COMBINE>
__global__ __launch_bounds__(256) void pullb_kernel(
    const int* __restrict__ rp, const int* __restrict__ degd,
    const int2* __restrict__ csr,
    const unsigned short* __restrict__ cur,   // gather source (h1 or h2)
    unsigned short* __restrict__ nxt,         // output (h2 or hc)
    const float* __restrict__ x,
    const unsigned short* __restrict__ h1,
    const float* __restrict__ coef, int N) {
    int wid = (int)((blockIdx.x * 256L + threadIdx.x) >> 6);
    if (wid >= N) return;
    int lane = threadIdx.x & 63;
    int g  = lane >> 4;       // 0..3
    int ls = lane & 15;       // elems [8ls, 8ls+8)
    int beg = __builtin_amdgcn_readfirstlane(rp[wid]);
    int cnt = __builtin_amdgcn_readfirstlane(degd[wid]);
    float acc[8] = {0.f, 0.f, 0.f, 0.f, 0.f, 0.f, 0.f, 0.f};
    if (cnt > 0) {
        for (int j = 0; j < cnt; j += 8) {
            int2 e0, e1; float w0, w1;
            {
                int jj = j + g;
                bool ok = jj < cnt;
                e0 = csr[beg + (ok ? jj : 0)];
                w0 = ok ? __int_as_float(e0.y) : 0.0f;
            }
            {
                int jj = j + 4 + g;
                bool ok = jj < cnt;
                e1 = csr[beg + (ok ? jj : 0)];
                w1 = ok ? __int_as_float(e1.y) : 0.0f;
            }
            s16x8 u0 = *(const s16x8*)(cur + (long)e0.x * C + ls * 8);
            s16x8 u1 = *(const s16x8*)(cur + (long)e1.x * C + ls * 8);
            #pragma unroll
            for (int k = 0; k < 8; ++k)
                acc[k] += w0 * b2f((unsigned short)u0[k]) + w1 * b2f((unsigned short)u1[k]);
        }
        #pragma unroll
        for (int k = 0; k < 8; ++k) acc[k] += __shfl_xor(acc[k], 16, 64);
        #pragma unroll
        for (int k = 0; k < 8; ++k) acc[k] += __shfl_xor(acc[k], 32, 64);
        float dv = rsqrtf((float)cnt);
        #pragma unroll
        for (int k = 0; k < 8; ++k) acc[k] *= dv;
    }
    if (g == 0) {
        long rb = (long)wid * C + ls * 8;
        float f[8];
        if (COMBINE) {
            float c0 = coef[0], c1 = coef[1], c2 = coef[2], c3 = coef[3];
            float4 xa = *(const float4*)(x + rb);
            float4 xb = *(const float4*)(x + rb + 4);
            s16x8 u1 = *(const s16x8*)(h1 + rb);
            s16x8 u2 = *(const s16x8*)(cur + rb);
            float xv[8] = {xa.x, xa.y, xa.z, xa.w, xb.x, xb.y, xb.z, xb.w};
            #pragma unroll
            for (int k = 0; k < 8; ++k)
                f[k] = c0 * xv[k] + c1 * b2f((unsigned short)u1[k])
                     + c2 * b2f((unsigned short)u2[k]) + c3 * acc[k];
        } else {
            #pragma unroll
            for (int k = 0; k < 8; ++k) f[k] = acc[k];
        }
        uint4 o;
        o.x = (unsigned int)f2b(f[0]) | ((unsigned int)f2b(f[1]) << 16);
        o.y = (unsigned int)f2b(f[2]) | ((unsigned int)f2b(f[3]) << 16);
        o.z = (unsigned int)f2b(f[4]) | ((unsigned int)f2b(f[5]) << 16);
        o.w = (unsigned int)f2b(f[6]) | ((unsigned int)f2b(f[7]) << 16);
        *(uint4*)(nxt + rb) = o;
    }
}

// ---------------- pure MFMA GEMM: out = hc @ W + bias ----------------
__global__ __launch_bounds__(256) void gemm_kernel(
    const unsigned short* __restrict__ hc,
    const unsigned short* __restrict__ WtB,
    const float* __restrict__ bias,
    float* __restrict__ out, int N) {
    __shared__ unsigned short Wl[128 * 136];   // 34816 B, padded rows
    int t = threadIdx.x;

    #pragma unroll
    for (int i = 0; i < 8; ++i) {
        int ch = t + i * 256;          // 0..2047
        int r = ch >> 4;               // 0..127 (col of W)
        int ko = (ch & 15) * 8;        // k offset
        *(s16x8*)(Wl + r * 136 + ko) = *(const s16x8*)(WtB + r * 128 + ko);
    }
    __syncthreads();

    int wave = t >> 6, lane = t & 63;
    int lsel = lane & 15;
    int lk   = (lane >> 4) * 8;
    int arow = blockIdx.x * 64 + wave * 16 + lsel;
    bool rok = arow < N;
    long rbase = (long)arow * C;

    f32x4 acc[8];
    #pragma unroll
    for (int i = 0; i < 8; ++i) acc[i] = (f32x4){0.f, 0.f, 0.f, 0.f};

    #pragma unroll
    for (int ks = 0; ks < 4; ++ks) {
        int k0 = ks * 32 + lk;
        s16x8 a = rok ? *(const s16x8*)(hc + rbase + k0) : (s16x8)0;
        #pragma unroll
        for (int cf = 0; cf < 8; ++cf) {
            s16x8 b = *(const s16x8*)(Wl + (cf * 16 + lsel) * 136 + k0);
            acc[cf] = __builtin_amdgcn_mfma_f32_16x16x32_bf16(a, b, acc[cf], 0, 0, 0);
        }
    }

    int orow0 = blockIdx.x * 64 + wave * 16 + (lane >> 4) * 4;
    #pragma unroll
    for (int cf = 0; cf < 8; ++cf) {
        int ocol = cf * 16 + lsel;
        float bv = bias[ocol];
        #pragma unroll
        for (int r = 0; r < 4; ++r) {
            int orow = orow0 + r;
            if (orow < N) out[(long)orow * C + ocol] = acc[cf][r] + bv;
        }
    }
}

extern "C" void kernel_launch(void* const* d_in, const int* in_sizes, int n_in,
                              void* d_out, int out_size, void* d_ws, size_t ws_size,
                              hipStream_t stream) {
    const float* x          = (const float*)d_in[0];
    const int*   ei         = (const int*)d_in[1];   // harness delivers int32
    const float* W          = (const float*)d_in[3];
    const float* bias       = (const float*)d_in[4];
    const float* log_scale  = (const float*)d_in[5];
    const float* hop_logits = (const float*)d_in[6];
    float* out = (float*)d_out;

    int N = in_sizes[0] / C;
    int E = in_sizes[1] / 2;

    char* ws = (char*)d_ws;
    size_t hb = (size_t)N * C * sizeof(unsigned short);   // 25.6 MB per bf16 buffer
    unsigned short* h1 = (unsigned short*)ws;
    unsigned short* h2 = (unsigned short*)(ws + hb);
    unsigned short* hc = (unsigned short*)(ws + 2 * hb);  // combined row buffer
    int2*  csr     = (int2*)(ws + 3 * hb);                // E entries
    int*   degs    = (int*)(csr + E);                     // [degs|degd|gctr16] zeroed together
    int*   degd    = degs + N;
    int*   gctr    = degd + N;            // 16 ints
    int*   rp      = gctr + 16;
    int*   cursor  = rp + N;
    float* coef    = (float*)(cursor + N);
    unsigned short* WtB = (unsigned short*)(coef + 4);    // 128*128 bf16

    int eb4 = (E / 4 + 255) / 256 + 1;    // 4 edges/thread kernels
    int nbk = (N + 255) / 256;
    int pull_blocks = (int)(((long)N * 64 + 255) / 256);

    // build: zero -> hist -> Wt/coef -> fused rp scan -> scatter
    long zn4 = (2L * N + 16 + 3) / 4;
    zero_int_kernel<<<(int)((zn4 + 255) / 256), 256, 0, stream>>>((int4*)degs, zn4);
    hist_kernel<<<eb4, 256, 0, stream>>>(ei, E, degs, degd);
    wt_kernel<<<64, 256, 0, stream>>>(W, WtB, log_scale, hop_logits, coef);
    rpscan_kernel<<<nbk, 256, 0, stream>>>(degd, rp, cursor, gctr, N);
    scatter_kernel<<<eb4, 256, 0, stream>>>(ei, E, cursor, degs, csr);

    // hop 1: f32 x, 2-row gathers
    pull1_kernel<<<pull_blocks, 256, 0, stream>>>(rp, degd, csr, x, (unsigned int*)h1, N);
    // hop 2: bf16, 4-row gathers
    pullb_kernel<0><<<pull_blocks, 256, 0, stream>>>(rp, degd, csr, h1, h2, x, h1, coef, N);
    // hop 3 + combine: hc = bf16(c0*x + c1*h1 + c2*h2 + c3*h3)
    pullb_kernel<1><<<pull_blocks, 256, 0, stream>>>(rp, degd, csr, h2, hc, x, h1, coef, N);

    // out = hc @ W + bias  (pure MFMA GEMM)
    gemm_kernel<<<(N + 63) / 64, 256, 0, stream>>>(hc, WtB, bias, out, N);
}